// Round 1
// baseline (386.764 us; speedup 1.0000x reference)
//
#include <hip/hip_runtime.h>
#include <hip/hip_bf16.h>

#define NR 1024
#define DV 2048
#define DMM 64
#define DO 2048

__device__ __forceinline__ float relu_f(float x) { return fmaxf(x, 0.f); }

// ---------------- Kernel 1: k = relu(fv)@Wk + bk ; q = relu(fv)@Wq + bq ----------------
// 256 blocks x 128 threads; each block handles 4 rows of fv (staged in LDS with relu),
// threads 0..63 compute k columns, 64..127 compute q columns. Weight reads coalesced, L2-hot.
__global__ __launch_bounds__(128) void kq_kernel(
    const float* __restrict__ fv,
    const float* __restrict__ Wk, const float* __restrict__ bk,
    const float* __restrict__ Wq, const float* __restrict__ bq,
    float* __restrict__ kout, float* __restrict__ qout)
{
    __shared__ float fvs[4][DV];
    const int t = threadIdx.x;
    const int r0 = blockIdx.x * 4;
    for (int idx = t; idx < 4 * (DV / 4); idx += 128) {
        int row = idx >> 9;          // DV/4 = 512 float4 per row
        int c4  = idx & 511;
        float4 v = *reinterpret_cast<const float4*>(&fv[(r0 + row) * DV + c4 * 4]);
        v.x = relu_f(v.x); v.y = relu_f(v.y); v.z = relu_f(v.z); v.w = relu_f(v.w);
        *reinterpret_cast<float4*>(&fvs[row][c4 * 4]) = v;
    }
    __syncthreads();
    const float* W = (t < 64) ? Wk : Wq;
    const int col = t & 63;
    float a0 = 0.f, a1 = 0.f, a2 = 0.f, a3 = 0.f;
    #pragma unroll 8
    for (int kk = 0; kk < DV; ++kk) {
        float w = W[kk * 64 + col];       // 64 lanes read consecutive addresses
        a0 = fmaf(fvs[0][kk], w, a0);     // LDS broadcast
        a1 = fmaf(fvs[1][kk], w, a1);
        a2 = fmaf(fvs[2][kk], w, a2);
        a3 = fmaf(fvs[3][kk], w, a3);
    }
    float b = (t < 64) ? bk[col] : bq[col];
    float* out = (t < 64) ? kout : qout;
    out[(r0 + 0) * 64 + col] = a0 + b;
    out[(r0 + 1) * 64 + col] = a1 + b;
    out[(r0 + 2) * 64 + col] = a2 + b;
    out[(r0 + 3) * 64 + col] = a3 + b;
}

// ---------------- Tiled fp32 GEMM: C[M,N] = op(A)[M,K] @ B[K,N] (+bias) ----------------
// BM=64 BN=128 BK=16, 256 threads, 4x8 micro-tile per thread.
// As stored transposed [kk][row] (pad 68 -> 16B-aligned rows, conflict-light writes),
// Bs [kk][col] (pad 132). Thread covers cols {tx*4..+3} U {64+tx*4..+3} (2-way max conflicts).
template<bool RELU_A, bool BIAS>
__global__ __launch_bounds__(256) void gemm_tiled(
    const float* __restrict__ A, const float* __restrict__ B,
    const float* __restrict__ bias, float* __restrict__ C,
    int M, int N, int K)
{
    __shared__ float As[16][68];
    __shared__ float Bs[16][132];
    const int t  = threadIdx.x;
    const int tx = t & 15;        // col group 0..15
    const int ty = t >> 4;        // row group 0..15
    const int bm0 = blockIdx.y * 64;
    const int bn0 = blockIdx.x * 128;
    const int arow = t >> 2, aq = t & 3;          // A tile: 64 rows x 4 float4
    const int bkk = t >> 5, bcolq = t & 31;       // B tile: rows (bkk, bkk+8) x 32 float4
    float acc[4][8] = {};
    for (int k0 = 0; k0 < K; k0 += 16) {
        float4 av = *reinterpret_cast<const float4*>(&A[(bm0 + arow) * K + k0 + aq * 4]);
        if (RELU_A) {
            av.x = fmaxf(av.x, 0.f); av.y = fmaxf(av.y, 0.f);
            av.z = fmaxf(av.z, 0.f); av.w = fmaxf(av.w, 0.f);
        }
        float4 b0 = *reinterpret_cast<const float4*>(&B[(k0 + bkk) * N + bn0 + bcolq * 4]);
        float4 b1 = *reinterpret_cast<const float4*>(&B[(k0 + bkk + 8) * N + bn0 + bcolq * 4]);
        As[aq * 4 + 0][arow] = av.x;
        As[aq * 4 + 1][arow] = av.y;
        As[aq * 4 + 2][arow] = av.z;
        As[aq * 4 + 3][arow] = av.w;
        *reinterpret_cast<float4*>(&Bs[bkk][bcolq * 4])     = b0;
        *reinterpret_cast<float4*>(&Bs[bkk + 8][bcolq * 4]) = b1;
        __syncthreads();
        #pragma unroll
        for (int kk = 0; kk < 16; ++kk) {
            float4 a  = *reinterpret_cast<const float4*>(&As[kk][ty * 4]);
            float4 p  = *reinterpret_cast<const float4*>(&Bs[kk][tx * 4]);
            float4 qq = *reinterpret_cast<const float4*>(&Bs[kk][64 + tx * 4]);
            float ar[4] = {a.x, a.y, a.z, a.w};
            float br[8] = {p.x, p.y, p.z, p.w, qq.x, qq.y, qq.z, qq.w};
            #pragma unroll
            for (int r = 0; r < 4; ++r)
                #pragma unroll
                for (int c = 0; c < 8; ++c)
                    acc[r][c] = fmaf(ar[r], br[c], acc[r][c]);
        }
        __syncthreads();
    }
    float4 bias0 = {0,0,0,0}, bias1 = {0,0,0,0};
    if (BIAS) {
        bias0 = *reinterpret_cast<const float4*>(&bias[bn0 + tx * 4]);
        bias1 = *reinterpret_cast<const float4*>(&bias[bn0 + 64 + tx * 4]);
    }
    #pragma unroll
    for (int r = 0; r < 4; ++r) {
        int row = bm0 + ty * 4 + r;
        float4 o0, o1;
        o0.x = acc[r][0] + bias0.x; o0.y = acc[r][1] + bias0.y;
        o0.z = acc[r][2] + bias0.z; o0.w = acc[r][3] + bias0.w;
        o1.x = acc[r][4] + bias1.x; o1.y = acc[r][5] + bias1.y;
        o1.z = acc[r][6] + bias1.z; o1.w = acc[r][7] + bias1.w;
        *reinterpret_cast<float4*>(&C[row * N + bn0 + tx * 4])      = o0;
        *reinterpret_cast<float4*>(&C[row * N + bn0 + 64 + tx * 4]) = o1;
    }
}

// ---------------- Kernel 3: attention row i: exp(<k_i,q_j>/8) * geoMLP(i,j), zero diag, normalize ----
// 1024 blocks x 128 threads; q staged in LDS in 8 chunks of 128 rows (stride 65: conflict-free).
__global__ __launch_bounds__(128) void attn_kernel(
    const float* __restrict__ kmat, const float* __restrict__ qmat,
    const float* __restrict__ rois,
    const float* __restrict__ G1, const float* __restrict__ g1,
    const float* __restrict__ G2, const float* __restrict__ g2,
    float* __restrict__ att)
{
    __shared__ float ks[64];
    __shared__ float G1s[256];
    __shared__ float g1s[64];
    __shared__ float G2s[64];
    __shared__ float qs[128][65];
    __shared__ float red[2];
    const int i = blockIdx.x;
    const int t = threadIdx.x;
    if (t < 64) { ks[t] = kmat[i * 64 + t]; g1s[t] = g1[t]; G2s[t] = G2[t]; }
    G1s[t] = G1[t];
    G1s[128 + t] = G1[128 + t];
    const float rix = rois[i * 4 + 0], riy = rois[i * 4 + 1];
    const float riz = rois[i * 4 + 2], riw = rois[i * 4 + 3];
    const float wi = riz - rix, hi_ = riw - riy;
    const float cxi = 0.5f * (rix + riz), cyi = 0.5f * (riy + riw);
    const float g2v = g2[0];
    float vals[8];
    float rsum = 0.f;
    #pragma unroll
    for (int ch = 0; ch < 8; ++ch) {
        const int jbase = ch * 128;
        __syncthreads();   // protect qs (and first-iter LDS init)
        for (int idx = t; idx < 128 * 16; idx += 128) {
            int row = idx >> 4, c4 = idx & 15;
            float4 v = *reinterpret_cast<const float4*>(&qmat[(jbase + row) * 64 + c4 * 4]);
            qs[row][c4 * 4 + 0] = v.x; qs[row][c4 * 4 + 1] = v.y;
            qs[row][c4 * 4 + 2] = v.z; qs[row][c4 * 4 + 3] = v.w;
        }
        __syncthreads();
        const int j = jbase + t;
        float dot = 0.f;
        #pragma unroll 16
        for (int c = 0; c < 64; ++c) dot = fmaf(ks[c], qs[t][c], dot);
        float vw = dot * 0.125f;   // 1/sqrt(64)
        float4 rj = *reinterpret_cast<const float4*>(&rois[j * 4]);
        float wj = rj.z - rj.x, hj = rj.w - rj.y;
        float f1 = logf(fabsf(0.5f * (rj.x + rj.z) - cxi) / wi + 1e-3f);
        float f2 = logf(fabsf(0.5f * (rj.y + rj.w) - cyi) / hi_ + 1e-3f);
        float f3 = logf(wj / wi);
        float f4 = logf(hj / hi_);
        float gw = 0.f;
        #pragma unroll 8
        for (int m = 0; m < 64; ++m) {
            float hm = g1s[m];
            hm = fmaf(f1, G1s[m], hm);
            hm = fmaf(f2, G1s[64 + m], hm);
            hm = fmaf(f3, G1s[128 + m], hm);
            hm = fmaf(f4, G1s[192 + m], hm);
            hm = fmaxf(hm, 0.f);
            gw = fmaf(hm, G2s[m], gw);
        }
        gw = fmaxf(gw + g2v, 0.f);
        float a = expf(vw) * gw;
        if (j == i) a = 0.f;
        vals[ch] = a;
        rsum += a;
    }
    float s = rsum;
    #pragma unroll
    for (int o = 32; o > 0; o >>= 1) s += __shfl_down(s, o, 64);
    if ((t & 63) == 0) red[t >> 6] = s;
    __syncthreads();
    const float inv = 1.f / (red[0] + red[1] + 1e-10f);
    #pragma unroll
    for (int ch = 0; ch < 8; ++ch)
        att[i * NR + ch * 128 + t] = vals[ch] * inv;
}

extern "C" void kernel_launch(void* const* d_in, const int* in_sizes, int n_in,
                              void* d_out, int out_size, void* d_ws, size_t ws_size,
                              hipStream_t stream) {
    const float* feat = (const float*)d_in[0];
    const float* rois = (const float*)d_in[1];
    const float* Wk   = (const float*)d_in[2];
    const float* bk   = (const float*)d_in[3];
    const float* Wq   = (const float*)d_in[4];
    const float* bq   = (const float*)d_in[5];
    const float* Wv   = (const float*)d_in[6];
    const float* bv   = (const float*)d_in[7];
    const float* G1   = (const float*)d_in[8];
    const float* g1   = (const float*)d_in[9];
    const float* G2   = (const float*)d_in[10];
    const float* g2   = (const float*)d_in[11];
    float* out = (float*)d_out;
    char* ws = (char*)d_ws;
    float* kbuf = (float*)(ws);                              // 1024x64   (256 KB)
    float* qbuf = (float*)(ws + 256 * 1024);                 // 1024x64   (256 KB)
    float* vbuf = (float*)(ws + 512 * 1024);                 // 1024x2048 (8 MB)
    float* abuf = (float*)(ws + 512 * 1024 + 8 * 1024 * 1024); // 1024x1024 (4 MB)

    kq_kernel<<<256, 128, 0, stream>>>(feat, Wk, bk, Wq, bq, kbuf, qbuf);
    gemm_tiled<true, true><<<dim3(DO / 128, NR / 64), 256, 0, stream>>>(
        feat, Wv, bv, vbuf, NR, DO, DV);
    attn_kernel<<<NR, 128, 0, stream>>>(kbuf, qbuf, rois, G1, g1, G2, g2, abuf);
    gemm_tiled<false, false><<<dim3(DO / 128, NR / 64), 256, 0, stream>>>(
        abuf, vbuf, nullptr, out, NR, DO, NR);
}

// Round 2
// 183.094 us; speedup vs baseline: 2.1124x; 2.1124x over previous
//
#include <hip/hip_runtime.h>
#include <hip/hip_bf16.h>

#define NR 1024
#define DV 2048
#define DMM 64
#define DO 2048

typedef __attribute__((ext_vector_type(8))) __bf16 bf16x8;
typedef __attribute__((ext_vector_type(4))) float f32x4;

__device__ __forceinline__ float relu_f(float x) { return fmaxf(x, 0.f); }

__device__ __forceinline__ unsigned short f2bf(float x) {
    union { float f; unsigned int u; } v; v.f = x;
    unsigned int r = v.u + 0x7fffu + ((v.u >> 16) & 1u);   // RNE (no NaN inputs here)
    return (unsigned short)(r >> 16);
}

__device__ __forceinline__ void gload_lds16(const void* g, void* l) {
    __builtin_amdgcn_global_load_lds(
        (const __attribute__((address_space(1))) void*)g,
        (__attribute__((address_space(3))) void*)l, 16, 0, 0);
}

// ---------------- fv -> bf16 with fused ReLU ----------------
__global__ __launch_bounds__(256) void convert_fv(const float* __restrict__ fv,
                                                  unsigned short* __restrict__ out) {
    const int idx = blockIdx.x * 256 + threadIdx.x;
    const float4 a = *reinterpret_cast<const float4*>(fv + (size_t)idx * 8);
    const float4 b = *reinterpret_cast<const float4*>(fv + (size_t)idx * 8 + 4);
    uint4 o;
    o.x = (unsigned)f2bf(relu_f(a.x)) | ((unsigned)f2bf(relu_f(a.y)) << 16);
    o.y = (unsigned)f2bf(relu_f(a.z)) | ((unsigned)f2bf(relu_f(a.w)) << 16);
    o.z = (unsigned)f2bf(relu_f(b.x)) | ((unsigned)f2bf(relu_f(b.y)) << 16);
    o.w = (unsigned)f2bf(relu_f(b.z)) | ((unsigned)f2bf(relu_f(b.w)) << 16);
    *reinterpret_cast<uint4*>(out + (size_t)idx * 8) = o;
}

// ---------------- Wv [DV][DO] fp32 -> WvT [DO][DV] bf16 (64x64 LDS tiles) ----------------
__global__ __launch_bounds__(256) void transpose_wv(const float* __restrict__ W,
                                                    unsigned short* __restrict__ Wt) {
    __shared__ float ld[64][65];   // [o_local][k_local]
    const int t = threadIdx.x;
    const int k0 = blockIdx.y * 64;
    const int o0 = blockIdx.x * 64;
    const int r = t >> 2;              // k_local
    const int c0 = (t & 3) * 16;       // o_local base
    #pragma unroll
    for (int i = 0; i < 4; ++i) {
        float4 v = *reinterpret_cast<const float4*>(&W[(size_t)(k0 + r) * DO + o0 + c0 + i * 4]);
        ld[c0 + i * 4 + 0][r] = v.x;
        ld[c0 + i * 4 + 1][r] = v.y;
        ld[c0 + i * 4 + 2][r] = v.z;
        ld[c0 + i * 4 + 3][r] = v.w;
    }
    __syncthreads();
    const int o = t >> 2;
    const int kc = (t & 3) * 16;
    unsigned int u[8];
    #pragma unroll
    for (int j = 0; j < 8; ++j) {
        float x0 = ld[o][kc + 2 * j], x1 = ld[o][kc + 2 * j + 1];
        u[j] = (unsigned)f2bf(x0) | ((unsigned)f2bf(x1) << 16);
    }
    uint4* dst = reinterpret_cast<uint4*>(&Wt[(size_t)(o0 + o) * DV + k0 + kc]);
    dst[0] = make_uint4(u[0], u[1], u[2], u[3]);
    dst[1] = make_uint4(u[4], u[5], u[6], u[7]);
}

// ---------------- k/q projections (fp32, unchanged from R1) ----------------
__global__ __launch_bounds__(128) void kq_kernel(
    const float* __restrict__ fv,
    const float* __restrict__ Wk, const float* __restrict__ bk,
    const float* __restrict__ Wq, const float* __restrict__ bq,
    float* __restrict__ kout, float* __restrict__ qout)
{
    __shared__ float fvs[4][DV];
    const int t = threadIdx.x;
    const int r0 = blockIdx.x * 4;
    for (int idx = t; idx < 4 * (DV / 4); idx += 128) {
        int row = idx >> 9;
        int c4  = idx & 511;
        float4 v = *reinterpret_cast<const float4*>(&fv[(r0 + row) * DV + c4 * 4]);
        v.x = relu_f(v.x); v.y = relu_f(v.y); v.z = relu_f(v.z); v.w = relu_f(v.w);
        *reinterpret_cast<float4*>(&fvs[row][c4 * 4]) = v;
    }
    __syncthreads();
    const float* W = (t < 64) ? Wk : Wq;
    const int col = t & 63;
    float a0 = 0.f, a1 = 0.f, a2 = 0.f, a3 = 0.f;
    #pragma unroll 8
    for (int kk = 0; kk < DV; ++kk) {
        float w = W[kk * 64 + col];
        a0 = fmaf(fvs[0][kk], w, a0);
        a1 = fmaf(fvs[1][kk], w, a1);
        a2 = fmaf(fvs[2][kk], w, a2);
        a3 = fmaf(fvs[3][kk], w, a3);
    }
    float b = (t < 64) ? bk[col] : bq[col];
    float* out = (t < 64) ? kout : qout;
    out[(r0 + 0) * 64 + col] = a0 + b;
    out[(r0 + 1) * 64 + col] = a1 + b;
    out[(r0 + 2) * 64 + col] = a2 + b;
    out[(r0 + 3) * 64 + col] = a3 + b;
}

// ---------------- attention row kernel (fp32 compute, bf16 out) ----------------
__global__ __launch_bounds__(128) void attn_kernel(
    const float* __restrict__ kmat, const float* __restrict__ qmat,
    const float* __restrict__ rois,
    const float* __restrict__ G1, const float* __restrict__ g1,
    const float* __restrict__ G2, const float* __restrict__ g2,
    unsigned short* __restrict__ att)
{
    __shared__ float ks[64];
    __shared__ float G1s[256];
    __shared__ float g1s[64];
    __shared__ float G2s[64];
    __shared__ float qs[128][65];
    __shared__ float red[2];
    const int i = blockIdx.x;
    const int t = threadIdx.x;
    if (t < 64) { ks[t] = kmat[i * 64 + t]; g1s[t] = g1[t]; G2s[t] = G2[t]; }
    G1s[t] = G1[t];
    G1s[128 + t] = G1[128 + t];
    const float rix = rois[i * 4 + 0], riy = rois[i * 4 + 1];
    const float riz = rois[i * 4 + 2], riw = rois[i * 4 + 3];
    const float wi = riz - rix, hi_ = riw - riy;
    const float cxi = 0.5f * (rix + riz), cyi = 0.5f * (riy + riw);
    const float g2v = g2[0];
    float vals[8];
    float rsum = 0.f;
    #pragma unroll
    for (int ch = 0; ch < 8; ++ch) {
        const int jbase = ch * 128;
        __syncthreads();
        for (int idx = t; idx < 128 * 16; idx += 128) {
            int row = idx >> 4, c4 = idx & 15;
            float4 v = *reinterpret_cast<const float4*>(&qmat[(jbase + row) * 64 + c4 * 4]);
            qs[row][c4 * 4 + 0] = v.x; qs[row][c4 * 4 + 1] = v.y;
            qs[row][c4 * 4 + 2] = v.z; qs[row][c4 * 4 + 3] = v.w;
        }
        __syncthreads();
        const int j = jbase + t;
        float dot = 0.f;
        #pragma unroll 16
        for (int c = 0; c < 64; ++c) dot = fmaf(ks[c], qs[t][c], dot);
        float vw = dot * 0.125f;
        float4 rj = *reinterpret_cast<const float4*>(&rois[j * 4]);
        float wj = rj.z - rj.x, hj = rj.w - rj.y;
        float f1 = logf(fabsf(0.5f * (rj.x + rj.z) - cxi) / wi + 1e-3f);
        float f2 = logf(fabsf(0.5f * (rj.y + rj.w) - cyi) / hi_ + 1e-3f);
        float f3 = logf(wj / wi);
        float f4 = logf(hj / hi_);
        float gw = 0.f;
        #pragma unroll 8
        for (int m = 0; m < 64; ++m) {
            float hm = g1s[m];
            hm = fmaf(f1, G1s[m], hm);
            hm = fmaf(f2, G1s[64 + m], hm);
            hm = fmaf(f3, G1s[128 + m], hm);
            hm = fmaf(f4, G1s[192 + m], hm);
            hm = fmaxf(hm, 0.f);
            gw = fmaf(hm, G2s[m], gw);
        }
        gw = fmaxf(gw + g2v, 0.f);
        float a = expf(vw) * gw;
        if (j == i) a = 0.f;
        vals[ch] = a;
        rsum += a;
    }
    float s = rsum;
    #pragma unroll
    for (int o = 32; o > 0; o >>= 1) s += __shfl_down(s, o, 64);
    if ((t & 63) == 0) red[t >> 6] = s;
    __syncthreads();
    const float inv = 1.f / (red[0] + red[1] + 1e-10f);
    #pragma unroll
    for (int ch = 0; ch < 8; ++ch)
        att[i * NR + ch * 128 + t] = f2bf(vals[ch] * inv);
}

// ---------------- bf16 MFMA GEMM: C[M][N] = A[M][K] @ Bt[N][K]^T ----------------
// BM=64 BN=128 BK=32, 4 waves (2x2), wave tile 32x64 = 2x4 16x16 frags.
// global_load_lds width-16 staging (linear LDS), 2 barriers per K-step (m97 structure).
// EPI 0: fp32 C, no bias.  EPI 1: bf16 C with bias[row].
template<int EPI>
__global__ __launch_bounds__(256) void gemm_bt_mfma(
    const unsigned short* __restrict__ A,
    const unsigned short* __restrict__ Bt,
    const float* __restrict__ bias,
    float* __restrict__ Cf,
    unsigned short* __restrict__ Cb,
    int M, int N, int K)
{
    __shared__ unsigned short As[64 * 32];
    __shared__ unsigned short Bs[128 * 32];
    const int t = threadIdx.x;
    const int w = t >> 6;
    const int lane = t & 63;
    const int wr = w >> 1, wc = w & 1;
    const int bm0 = blockIdx.y * 64;
    const int bn0 = blockIdx.x * 128;

    // staging: wave w -> A rows [w*16, w*16+16), B rows [2w*16,..) and [(2w+1)*16,..)
    const int srow = lane >> 2;
    const int scol = (lane & 3) * 8;
    const unsigned short* ga  = A  + (size_t)(bm0 + w * 16 + srow) * K + scol;
    const unsigned short* gb0 = Bt + (size_t)(bn0 + (2 * w) * 16 + srow) * K + scol;
    const unsigned short* gb1 = Bt + (size_t)(bn0 + (2 * w + 1) * 16 + srow) * K + scol;
    unsigned short* la  = &As[w * 512];
    unsigned short* lb0 = &Bs[(2 * w) * 512];
    unsigned short* lb1 = &Bs[(2 * w + 1) * 512];

    const int fr = lane & 15;
    const int fq = lane >> 4;

    f32x4 acc[2][4] = {};

    for (int k0 = 0; k0 < K; k0 += 32) {
        gload_lds16(ga + k0, la);
        gload_lds16(gb0 + k0, lb0);
        gload_lds16(gb1 + k0, lb1);
        __syncthreads();
        bf16x8 af[2], bfr[4];
        #pragma unroll
        for (int m = 0; m < 2; ++m)
            af[m] = *reinterpret_cast<const bf16x8*>(&As[(wr * 32 + m * 16 + fr) * 32 + fq * 8]);
        #pragma unroll
        for (int n = 0; n < 4; ++n)
            bfr[n] = *reinterpret_cast<const bf16x8*>(&Bs[(wc * 64 + n * 16 + fr) * 32 + fq * 8]);
        #pragma unroll
        for (int m = 0; m < 2; ++m)
            #pragma unroll
            for (int n = 0; n < 4; ++n)
                acc[m][n] = __builtin_amdgcn_mfma_f32_16x16x32_bf16(af[m], bfr[n], acc[m][n], 0, 0, 0);
        __syncthreads();
    }

    #pragma unroll
    for (int m = 0; m < 2; ++m) {
        #pragma unroll
        for (int r = 0; r < 4; ++r) {
            const int row = bm0 + wr * 32 + m * 16 + fq * 4 + r;
            const float badd = (EPI == 1) ? bias[row] : 0.f;
            #pragma unroll
            for (int n = 0; n < 4; ++n) {
                const int col = bn0 + wc * 64 + n * 16 + fr;
                const float val = acc[m][n][r] + badd;
                if (EPI == 0) Cf[(size_t)row * N + col] = val;
                else          Cb[(size_t)row * N + col] = f2bf(val);
            }
        }
    }
}

extern "C" void kernel_launch(void* const* d_in, const int* in_sizes, int n_in,
                              void* d_out, int out_size, void* d_ws, size_t ws_size,
                              hipStream_t stream) {
    const float* feat = (const float*)d_in[0];
    const float* rois = (const float*)d_in[1];
    const float* Wk   = (const float*)d_in[2];
    const float* bk   = (const float*)d_in[3];
    const float* Wq   = (const float*)d_in[4];
    const float* bq   = (const float*)d_in[5];
    const float* Wv   = (const float*)d_in[6];
    const float* bv   = (const float*)d_in[7];
    const float* G1   = (const float*)d_in[8];
    const float* g1   = (const float*)d_in[9];
    const float* G2   = (const float*)d_in[10];
    const float* g2   = (const float*)d_in[11];
    float* out = (float*)d_out;
    char* ws = (char*)d_ws;

    float* kbuf          = (float*)ws;                                          // 256 KB
    float* qbuf          = (float*)(ws + (256 << 10));                          // 256 KB
    unsigned short* fvb  = (unsigned short*)(ws + (512 << 10));                 // 4 MB
    unsigned short* WvT  = (unsigned short*)(ws + (512 << 10) + (4 << 20));     // 8 MB
    unsigned short* vT   = (unsigned short*)(ws + (512 << 10) + (12 << 20));    // 4 MB
    unsigned short* attb = (unsigned short*)(ws + (512 << 10) + (16 << 20));    // 2 MB

    convert_fv<<<NR * DV / (256 * 8), 256, 0, stream>>>(feat, fvb);
    transpose_wv<<<dim3(DO / 64, DV / 64), 256, 0, stream>>>(Wv, WvT);
    kq_kernel<<<256, 128, 0, stream>>>(feat, Wk, bk, Wq, bq, kbuf, qbuf);
    // vT[DO][NR] = WvT[DO][DV] @ fvb[NR][DV]^T  (+bv per row)
    gemm_bt_mfma<1><<<dim3(NR / 128, DO / 64), 256, 0, stream>>>(
        WvT, fvb, bv, nullptr, vT, DO, NR, DV);
    attn_kernel<<<NR, 128, 0, stream>>>(kbuf, qbuf, rois, G1, g1, G2, g2, attb);
    // out[NR][DO] = attb[NR][NR] @ vT[DO][NR]^T
    gemm_bt_mfma<0><<<dim3(DO / 128, NR / 64), 256, 0, stream>>>(
        attb, vT, nullptr, out, nullptr, NR, DO, NR);
}

// Round 3
// 142.360 us; speedup vs baseline: 2.7168x; 1.2861x over previous
//
#include <hip/hip_runtime.h>
#include <hip/hip_bf16.h>

#define NR 1024
#define DV 2048
#define DMM 64
#define DO 2048

typedef __attribute__((ext_vector_type(8))) __bf16 bf16x8;
typedef __attribute__((ext_vector_type(4))) float f32x4;

__device__ __forceinline__ float relu_f(float x) { return fmaxf(x, 0.f); }

__device__ __forceinline__ unsigned short f2bf(float x) {
    union { float f; unsigned int u; } v; v.f = x;
    unsigned int r = v.u + 0x7fffu + ((v.u >> 16) & 1u);   // RNE (no NaN inputs here)
    return (unsigned short)(r >> 16);
}

__device__ __forceinline__ void gload_lds16(const void* g, void* l) {
    __builtin_amdgcn_global_load_lds(
        (const __attribute__((address_space(1))) void*)g,
        (__attribute__((address_space(3))) void*)l, 16, 0, 0);
}

// ---------------- fv -> bf16 with fused ReLU ----------------
__global__ __launch_bounds__(256) void convert_fv(const float* __restrict__ fv,
                                                  unsigned short* __restrict__ out) {
    const int idx = blockIdx.x * 256 + threadIdx.x;
    const float4 a = *reinterpret_cast<const float4*>(fv + (size_t)idx * 8);
    const float4 b = *reinterpret_cast<const float4*>(fv + (size_t)idx * 8 + 4);
    uint4 o;
    o.x = (unsigned)f2bf(relu_f(a.x)) | ((unsigned)f2bf(relu_f(a.y)) << 16);
    o.y = (unsigned)f2bf(relu_f(a.z)) | ((unsigned)f2bf(relu_f(a.w)) << 16);
    o.z = (unsigned)f2bf(relu_f(b.x)) | ((unsigned)f2bf(relu_f(b.y)) << 16);
    o.w = (unsigned)f2bf(relu_f(b.z)) | ((unsigned)f2bf(relu_f(b.w)) << 16);
    *reinterpret_cast<uint4*>(out + (size_t)idx * 8) = o;
}

// ---------- W [K][Ncols] fp32 -> Wt [Ncols][K] bf16 (64x64 LDS tiles) ----------
__global__ __launch_bounds__(256) void transpose_to_bt(const float* __restrict__ W,
                                                       unsigned short* __restrict__ Wt,
                                                       int Ncols, int K) {
    __shared__ float ld[64][65];   // [o_local][k_local]
    const int t = threadIdx.x;
    const int k0 = blockIdx.y * 64;
    const int o0 = blockIdx.x * 64;
    const int r = t >> 2;              // k_local
    const int c0 = (t & 3) * 16;       // o_local base
    #pragma unroll
    for (int i = 0; i < 4; ++i) {
        float4 v = *reinterpret_cast<const float4*>(&W[(size_t)(k0 + r) * Ncols + o0 + c0 + i * 4]);
        ld[c0 + i * 4 + 0][r] = v.x;
        ld[c0 + i * 4 + 1][r] = v.y;
        ld[c0 + i * 4 + 2][r] = v.z;
        ld[c0 + i * 4 + 3][r] = v.w;
    }
    __syncthreads();
    const int o = t >> 2;
    const int kc = (t & 3) * 16;
    unsigned int u[8];
    #pragma unroll
    for (int j = 0; j < 8; ++j) {
        float x0 = ld[o][kc + 2 * j], x1 = ld[o][kc + 2 * j + 1];
        u[j] = (unsigned)f2bf(x0) | ((unsigned)f2bf(x1) << 16);
    }
    uint4* dst = reinterpret_cast<uint4*>(&Wt[(size_t)(o0 + o) * K + k0 + kc]);
    dst[0] = make_uint4(u[0], u[1], u[2], u[3]);
    dst[1] = make_uint4(u[4], u[5], u[6], u[7]);
}

// ---------------- attention row kernel (fp32 compute, bf16 out) ----------------
// k_i = kq[i*128 + c], q_j = kq[j*128 + 64 + c]
__global__ __launch_bounds__(128) void attn_kernel(
    const float* __restrict__ kq,
    const float* __restrict__ rois,
    const float* __restrict__ G1, const float* __restrict__ g1,
    const float* __restrict__ G2, const float* __restrict__ g2,
    unsigned short* __restrict__ att)
{
    __shared__ float ks[64];
    __shared__ float G1s[256];
    __shared__ float g1s[64];
    __shared__ float G2s[64];
    __shared__ float qs[128][65];
    __shared__ float red[2];
    const int i = blockIdx.x;
    const int t = threadIdx.x;
    if (t < 64) { ks[t] = kq[i * 128 + t]; g1s[t] = g1[t]; G2s[t] = G2[t]; }
    G1s[t] = G1[t];
    G1s[128 + t] = G1[128 + t];
    const float rix = rois[i * 4 + 0], riy = rois[i * 4 + 1];
    const float riz = rois[i * 4 + 2], riw = rois[i * 4 + 3];
    const float wi = riz - rix, hi_ = riw - riy;
    const float cxi = 0.5f * (rix + riz), cyi = 0.5f * (riy + riw);
    const float g2v = g2[0];
    float vals[8];
    float rsum = 0.f;
    #pragma unroll
    for (int ch = 0; ch < 8; ++ch) {
        const int jbase = ch * 128;
        __syncthreads();
        for (int idx = t; idx < 128 * 16; idx += 128) {
            int row = idx >> 4, c4 = idx & 15;
            float4 v = *reinterpret_cast<const float4*>(&kq[(jbase + row) * 128 + 64 + c4 * 4]);
            qs[row][c4 * 4 + 0] = v.x; qs[row][c4 * 4 + 1] = v.y;
            qs[row][c4 * 4 + 2] = v.z; qs[row][c4 * 4 + 3] = v.w;
        }
        __syncthreads();
        const int j = jbase + t;
        float dot = 0.f;
        #pragma unroll 16
        for (int c = 0; c < 64; ++c) dot = fmaf(ks[c], qs[t][c], dot);
        float vw = dot * 0.125f;
        float4 rj = *reinterpret_cast<const float4*>(&rois[j * 4]);
        float wj = rj.z - rj.x, hj = rj.w - rj.y;
        float f1 = logf(fabsf(0.5f * (rj.x + rj.z) - cxi) / wi + 1e-3f);
        float f2 = logf(fabsf(0.5f * (rj.y + rj.w) - cyi) / hi_ + 1e-3f);
        float f3 = logf(wj / wi);
        float f4 = logf(hj / hi_);
        float gw = 0.f;
        #pragma unroll 8
        for (int m = 0; m < 64; ++m) {
            float hm = g1s[m];
            hm = fmaf(f1, G1s[m], hm);
            hm = fmaf(f2, G1s[64 + m], hm);
            hm = fmaf(f3, G1s[128 + m], hm);
            hm = fmaf(f4, G1s[192 + m], hm);
            hm = fmaxf(hm, 0.f);
            gw = fmaf(hm, G2s[m], gw);
        }
        gw = fmaxf(gw + g2v, 0.f);
        float a = expf(vw) * gw;
        if (j == i) a = 0.f;
        vals[ch] = a;
        rsum += a;
    }
    float s = rsum;
    #pragma unroll
    for (int o = 32; o > 0; o >>= 1) s += __shfl_down(s, o, 64);
    if ((t & 63) == 0) red[t >> 6] = s;
    __syncthreads();
    const float inv = 1.f / (red[0] + red[1] + 1e-10f);
    #pragma unroll
    for (int ch = 0; ch < 8; ++ch)
        att[i * NR + ch * 128 + t] = f2bf(vals[ch] * inv);
}

// ---------------- bf16 MFMA GEMM: C[M][N] = A[M][K] @ Bt[N][K]^T ----------------
// BM=64 BN=128 BK=32, 4 waves (2x2), wave tile 32x64 = 2x4 16x16 frags.
// EPI 0: fp32 C, no bias.  EPI 1: bf16 C with bias[row].  EPI 2: fp32 C with
// per-col bias (bias for col<64, bias2 for col>=64).
template<int EPI>
__global__ __launch_bounds__(256) void gemm_bt_mfma(
    const unsigned short* __restrict__ A,
    const unsigned short* __restrict__ Bt,
    const float* __restrict__ bias, const float* __restrict__ bias2,
    float* __restrict__ Cf,
    unsigned short* __restrict__ Cb,
    int M, int N, int K)
{
    __shared__ unsigned short As[64 * 32];
    __shared__ unsigned short Bs[128 * 32];
    const int t = threadIdx.x;
    const int w = t >> 6;
    const int lane = t & 63;
    const int wr = w >> 1, wc = w & 1;
    const int bm0 = blockIdx.y * 64;
    const int bn0 = blockIdx.x * 128;

    const int srow = lane >> 2;
    const int scol = (lane & 3) * 8;
    const unsigned short* ga  = A  + (size_t)(bm0 + w * 16 + srow) * K + scol;
    const unsigned short* gb0 = Bt + (size_t)(bn0 + (2 * w) * 16 + srow) * K + scol;
    const unsigned short* gb1 = Bt + (size_t)(bn0 + (2 * w + 1) * 16 + srow) * K + scol;
    unsigned short* la  = &As[w * 512];
    unsigned short* lb0 = &Bs[(2 * w) * 512];
    unsigned short* lb1 = &Bs[(2 * w + 1) * 512];

    const int fr = lane & 15;
    const int fq = lane >> 4;

    f32x4 acc[2][4] = {};

    for (int k0 = 0; k0 < K; k0 += 32) {
        gload_lds16(ga + k0, la);
        gload_lds16(gb0 + k0, lb0);
        gload_lds16(gb1 + k0, lb1);
        __syncthreads();
        bf16x8 af[2], bfr[4];
        #pragma unroll
        for (int m = 0; m < 2; ++m)
            af[m] = *reinterpret_cast<const bf16x8*>(&As[(wr * 32 + m * 16 + fr) * 32 + fq * 8]);
        #pragma unroll
        for (int n = 0; n < 4; ++n)
            bfr[n] = *reinterpret_cast<const bf16x8*>(&Bs[(wc * 64 + n * 16 + fr) * 32 + fq * 8]);
        #pragma unroll
        for (int m = 0; m < 2; ++m)
            #pragma unroll
            for (int n = 0; n < 4; ++n)
                acc[m][n] = __builtin_amdgcn_mfma_f32_16x16x32_bf16(af[m], bfr[n], acc[m][n], 0, 0, 0);
        __syncthreads();
    }

    #pragma unroll
    for (int m = 0; m < 2; ++m) {
        #pragma unroll
        for (int r = 0; r < 4; ++r) {
            const int row = bm0 + wr * 32 + m * 16 + fq * 4 + r;
            const float badd_row = (EPI == 1) ? bias[row] : 0.f;
            #pragma unroll
            for (int n = 0; n < 4; ++n) {
                const int col = bn0 + wc * 64 + n * 16 + fr;
                float val = acc[m][n][r];
                if (EPI == 1) val += badd_row;
                if (EPI == 2) val += (col < 64) ? bias[col] : bias2[col - 64];
                if (EPI == 1) Cb[(size_t)row * N + col] = f2bf(val);
                else          Cf[(size_t)row * N + col] = val;
            }
        }
    }
}

extern "C" void kernel_launch(void* const* d_in, const int* in_sizes, int n_in,
                              void* d_out, int out_size, void* d_ws, size_t ws_size,
                              hipStream_t stream) {
    const float* feat = (const float*)d_in[0];
    const float* rois = (const float*)d_in[1];
    const float* Wk   = (const float*)d_in[2];
    const float* bk   = (const float*)d_in[3];
    const float* Wq   = (const float*)d_in[4];
    const float* bq   = (const float*)d_in[5];
    const float* Wv   = (const float*)d_in[6];
    const float* bv   = (const float*)d_in[7];
    const float* G1   = (const float*)d_in[8];
    const float* g1   = (const float*)d_in[9];
    const float* G2   = (const float*)d_in[10];
    const float* g2   = (const float*)d_in[11];
    float* out = (float*)d_out;
    char* ws = (char*)d_ws;

    float* kqbuf         = (float*)ws;                                          // 1024x128 fp32 (512 KB)
    unsigned short* fvb  = (unsigned short*)(ws + (512 << 10));                 // 4 MB
    unsigned short* WvT  = (unsigned short*)(ws + (512 << 10) + (4 << 20));     // 8 MB
    unsigned short* WkqT = (unsigned short*)(ws + (512 << 10) + (12 << 20));    // 128x2048 bf16 (512 KB)
    unsigned short* vT   = (unsigned short*)(ws + (1024 << 10) + (12 << 20));   // 4 MB
    unsigned short* attb = (unsigned short*)(ws + (1024 << 10) + (16 << 20));   // 2 MB

    convert_fv<<<NR * DV / (256 * 8), 256, 0, stream>>>(feat, fvb);
    transpose_to_bt<<<dim3(1, DV / 64), 256, 0, stream>>>(Wk, WkqT, DMM, DV);
    transpose_to_bt<<<dim3(1, DV / 64), 256, 0, stream>>>(Wq, WkqT + 64 * DV, DMM, DV);
    transpose_to_bt<<<dim3(DO / 64, DV / 64), 256, 0, stream>>>(Wv, WvT, DO, DV);

    // kq[NR][128] = fvb[NR][DV] @ WkqT[128][DV]^T (+bk|bq per col), fp32 out
    gemm_bt_mfma<2><<<dim3(1, NR / 64), 256, 0, stream>>>(
        fvb, WkqT, bk, bq, kqbuf, nullptr, NR, 128, DV);
    // vT[DO][NR] = WvT[DO][DV] @ fvb[NR][DV]^T (+bv per row), bf16 out
    gemm_bt_mfma<1><<<dim3(NR / 128, DO / 64), 256, 0, stream>>>(
        WvT, fvb, bv, nullptr, nullptr, vT, DO, NR, DV);
    attn_kernel<<<NR, 128, 0, stream>>>(kqbuf, rois, G1, g1, G2, g2, attb);
    // out[NR][DO] = attb[NR][NR] @ vT[DO][NR]^T
    gemm_bt_mfma<0><<<dim3(DO / 128, NR / 64), 256, 0, stream>>>(
        attb, vT, nullptr, nullptr, out, nullptr, NR, DO, NR);
}

// Round 4
// 109.348 us; speedup vs baseline: 3.5370x; 1.3019x over previous
//
#include <hip/hip_runtime.h>
#include <hip/hip_bf16.h>

#define NR 1024
#define DV 2048
#define DMM 64
#define DO 2048

typedef __attribute__((ext_vector_type(8))) __bf16 bf16x8;
typedef __attribute__((ext_vector_type(4))) float f32x4;

__device__ __forceinline__ float relu_f(float x) { return fmaxf(x, 0.f); }

__device__ __forceinline__ unsigned short f2bf(float x) {
    union { float f; unsigned int u; } v; v.f = x;
    unsigned int r = v.u + 0x7fffu + ((v.u >> 16) & 1u);   // RNE
    return (unsigned short)(r >> 16);
}

__device__ __forceinline__ void gload_lds16(const void* g, void* l) {
    __builtin_amdgcn_global_load_lds(
        (const __attribute__((address_space(1))) void*)g,
        (__attribute__((address_space(3))) void*)l, 16, 0, 0);
}

// ---------------- prep: fused convert_fv + 3 weight transposes, one launch ----------------
__device__ __forceinline__ void transpose_tile(
    const float* __restrict__ W, unsigned short* __restrict__ Wt,
    int Ncols, int k0, int o0, float (*ld)[65])
{
    const int t = threadIdx.x;
    const int r = t >> 2;
    const int c0 = (t & 3) * 16;
    #pragma unroll
    for (int i = 0; i < 4; ++i) {
        float4 v = *reinterpret_cast<const float4*>(&W[(size_t)(k0 + r) * Ncols + o0 + c0 + i * 4]);
        ld[c0 + i * 4 + 0][r] = v.x;
        ld[c0 + i * 4 + 1][r] = v.y;
        ld[c0 + i * 4 + 2][r] = v.z;
        ld[c0 + i * 4 + 3][r] = v.w;
    }
    __syncthreads();
    const int o = t >> 2;
    const int kc = (t & 3) * 16;
    unsigned int u[8];
    #pragma unroll
    for (int j = 0; j < 8; ++j) {
        float x0 = ld[o][kc + 2 * j], x1 = ld[o][kc + 2 * j + 1];
        u[j] = (unsigned)f2bf(x0) | ((unsigned)f2bf(x1) << 16);
    }
    uint4* dst = reinterpret_cast<uint4*>(&Wt[(size_t)(o0 + o) * DV + k0 + kc]);
    dst[0] = make_uint4(u[0], u[1], u[2], u[3]);
    dst[1] = make_uint4(u[4], u[5], u[6], u[7]);
}

__global__ __launch_bounds__(256) void prep_kernel(
    const float* __restrict__ feat,
    const float* __restrict__ Wk, const float* __restrict__ Wq, const float* __restrict__ Wv,
    unsigned short* __restrict__ fvb, unsigned short* __restrict__ WkqT,
    unsigned short* __restrict__ WvT)
{
    __shared__ float ld[64][65];
    const int bid = blockIdx.x;
    if (bid < 1024) {
        const int idx = bid * 256 + threadIdx.x;
        const float4 a = *reinterpret_cast<const float4*>(feat + (size_t)idx * 8);
        const float4 b = *reinterpret_cast<const float4*>(feat + (size_t)idx * 8 + 4);
        uint4 o;
        o.x = (unsigned)f2bf(relu_f(a.x)) | ((unsigned)f2bf(relu_f(a.y)) << 16);
        o.y = (unsigned)f2bf(relu_f(a.z)) | ((unsigned)f2bf(relu_f(a.w)) << 16);
        o.z = (unsigned)f2bf(relu_f(b.x)) | ((unsigned)f2bf(relu_f(b.y)) << 16);
        o.w = (unsigned)f2bf(relu_f(b.z)) | ((unsigned)f2bf(relu_f(b.w)) << 16);
        *reinterpret_cast<uint4*>(fvb + (size_t)idx * 8) = o;
    } else if (bid < 2048) {
        const int idx = bid - 1024;                 // 32x32 tiles of Wv
        transpose_tile(Wv, WvT, DO, (idx >> 5) * 64, (idx & 31) * 64, ld);
    } else if (bid < 2080) {
        transpose_tile(Wk, WkqT, DMM, (bid - 2048) * 64, 0, ld);
    } else {
        transpose_tile(Wq, WkqT + 64 * DV, DMM, (bid - 2080) * 64, 0, ld);
    }
}

// ---------------- 128x128 MFMA tile core: acc += A[bm0..][K] @ Bt[bn0..][K]^T ----------------
__device__ __forceinline__ void mfma_tile_128(
    const unsigned short* __restrict__ A, const unsigned short* __restrict__ Bt, int K,
    int bm0, int bn0, unsigned short* As, unsigned short* Bs, f32x4 (&acc)[4][4])
{
    const int t = threadIdx.x;
    const int w = t >> 6, lane = t & 63;
    const int wr = w >> 1, wc = w & 1;
    const int srow = lane >> 2, scol = (lane & 3) * 8;
    const int fr = lane & 15, fq = lane >> 4;

    const unsigned short* ga0 = A  + (size_t)(bm0 + w * 16 + srow) * K + scol;
    const unsigned short* ga1 = A  + (size_t)(bm0 + 64 + w * 16 + srow) * K + scol;
    const unsigned short* gb0 = Bt + (size_t)(bn0 + w * 16 + srow) * K + scol;
    const unsigned short* gb1 = Bt + (size_t)(bn0 + 64 + w * 16 + srow) * K + scol;
    unsigned short* la0 = &As[(w * 16) * 32];
    unsigned short* la1 = &As[(64 + w * 16) * 32];
    unsigned short* lb0 = &Bs[(w * 16) * 32];
    unsigned short* lb1 = &Bs[(64 + w * 16) * 32];

    for (int k0 = 0; k0 < K; k0 += 32) {
        gload_lds16(ga0 + k0, la0);
        gload_lds16(ga1 + k0, la1);
        gload_lds16(gb0 + k0, lb0);
        gload_lds16(gb1 + k0, lb1);
        __syncthreads();
        bf16x8 af[4], bfr[4];
        #pragma unroll
        for (int m = 0; m < 4; ++m)
            af[m] = *reinterpret_cast<const bf16x8*>(&As[(wr * 64 + m * 16 + fr) * 32 + fq * 8]);
        #pragma unroll
        for (int n = 0; n < 4; ++n)
            bfr[n] = *reinterpret_cast<const bf16x8*>(&Bs[(wc * 64 + n * 16 + fr) * 32 + fq * 8]);
        #pragma unroll
        for (int m = 0; m < 4; ++m)
            #pragma unroll
            for (int n = 0; n < 4; ++n)
                acc[m][n] = __builtin_amdgcn_mfma_f32_16x16x32_bf16(af[m], bfr[n], acc[m][n], 0, 0, 0);
        __syncthreads();
    }
}

// ---------------- fused vT GEMM (128 blocks) + kq GEMM (8 blocks) ----------------
// vT[DO][NR] = WvT[DO][DV] @ fvb[NR][DV]^T + bv[row]      (bf16 out)
// kq[NR][128] = fvb[NR][DV] @ WkqT[128][DV]^T + {bk|bq}[col] (fp32 out)
__global__ __launch_bounds__(256) void gemm_vt_kq(
    const unsigned short* __restrict__ WvT, const unsigned short* __restrict__ fvb,
    const unsigned short* __restrict__ WkqT,
    const float* __restrict__ bv, const float* __restrict__ bk, const float* __restrict__ bq,
    unsigned short* __restrict__ vT, float* __restrict__ kq)
{
    __shared__ unsigned short As[128 * 32];
    __shared__ unsigned short Bs[128 * 32];
    const int bid = blockIdx.x;
    const bool is_kq = bid >= 128;
    const unsigned short* A  = is_kq ? fvb  : WvT;
    const unsigned short* Bt = is_kq ? WkqT : fvb;
    const int bm0 = is_kq ? (bid - 128) * 128 : (bid >> 3) * 128;
    const int bn0 = is_kq ? 0 : (bid & 7) * 128;

    f32x4 acc[4][4] = {};
    mfma_tile_128(A, Bt, DV, bm0, bn0, As, Bs, acc);

    const int t = threadIdx.x;
    const int w = t >> 6, lane = t & 63;
    const int wr = w >> 1, wc = w & 1;
    const int fr = lane & 15, fq = lane >> 4;
    if (!is_kq) {
        #pragma unroll
        for (int m = 0; m < 4; ++m)
            #pragma unroll
            for (int r = 0; r < 4; ++r) {
                const int row = bm0 + wr * 64 + m * 16 + fq * 4 + r;
                const float badd = bv[row];
                #pragma unroll
                for (int n = 0; n < 4; ++n) {
                    const int col = bn0 + wc * 64 + n * 16 + fr;
                    vT[(size_t)row * NR + col] = f2bf(acc[m][n][r] + badd);
                }
            }
    } else {
        #pragma unroll
        for (int m = 0; m < 4; ++m)
            #pragma unroll
            for (int r = 0; r < 4; ++r) {
                const int row = bm0 + wr * 64 + m * 16 + fq * 4 + r;
                #pragma unroll
                for (int n = 0; n < 4; ++n) {
                    const int col = wc * 64 + n * 16 + fr;
                    const float badd = (col < 64) ? bk[col] : bq[col - 64];
                    kq[(size_t)row * 128 + col] = acc[m][n][r] + badd;
                }
            }
    }
}

// ---------------- out GEMM: out[NR][DO] = attb[NR][NR] @ vT[DO][NR]^T ----------------
__global__ __launch_bounds__(256) void gemm_out(
    const unsigned short* __restrict__ attb, const unsigned short* __restrict__ vT,
    float* __restrict__ out)
{
    __shared__ unsigned short As[128 * 32];
    __shared__ unsigned short Bs[128 * 32];
    const int bm0 = blockIdx.y * 128;
    const int bn0 = blockIdx.x * 128;
    f32x4 acc[4][4] = {};
    mfma_tile_128(attb, vT, NR, bm0, bn0, As, Bs, acc);
    const int t = threadIdx.x;
    const int w = t >> 6, lane = t & 63;
    const int wr = w >> 1, wc = w & 1;
    const int fr = lane & 15, fq = lane >> 4;
    #pragma unroll
    for (int m = 0; m < 4; ++m)
        #pragma unroll
        for (int r = 0; r < 4; ++r) {
            const int row = bm0 + wr * 64 + m * 16 + fq * 4 + r;
            #pragma unroll
            for (int n = 0; n < 4; ++n) {
                const int col = bn0 + wc * 64 + n * 16 + fr;
                out[(size_t)row * DO + col] = acc[m][n][r];
            }
        }
}

// ---------------- attention row kernel (fp32 compute, bf16 out) ----------------
__global__ __launch_bounds__(128) void attn_kernel(
    const float* __restrict__ kq,
    const float* __restrict__ rois,
    const float* __restrict__ G1, const float* __restrict__ g1,
    const float* __restrict__ G2, const float* __restrict__ g2,
    unsigned short* __restrict__ att)
{
    __shared__ float ks[64];
    __shared__ float G1s[256];
    __shared__ float g1s[64];
    __shared__ float G2s[64];
    __shared__ float qs[128][65];
    __shared__ float red[2];
    const int i = blockIdx.x;
    const int t = threadIdx.x;
    if (t < 64) { ks[t] = kq[i * 128 + t]; g1s[t] = g1[t]; G2s[t] = G2[t]; }
    G1s[t] = G1[t];
    G1s[128 + t] = G1[128 + t];
    const float rix = rois[i * 4 + 0], riy = rois[i * 4 + 1];
    const float riz = rois[i * 4 + 2], riw = rois[i * 4 + 3];
    const float wi = riz - rix, hi_ = riw - riy;
    const float cxi = 0.5f * (rix + riz), cyi = 0.5f * (riy + riw);
    const float g2v = g2[0];
    float vals[8];
    float rsum = 0.f;
    #pragma unroll
    for (int ch = 0; ch < 8; ++ch) {
        const int jbase = ch * 128;
        __syncthreads();
        for (int idx = t; idx < 128 * 16; idx += 128) {
            int row = idx >> 4, c4 = idx & 15;
            float4 v = *reinterpret_cast<const float4*>(&kq[(jbase + row) * 128 + 64 + c4 * 4]);
            qs[row][c4 * 4 + 0] = v.x; qs[row][c4 * 4 + 1] = v.y;
            qs[row][c4 * 4 + 2] = v.z; qs[row][c4 * 4 + 3] = v.w;
        }
        __syncthreads();
        const int j = jbase + t;
        float dot = 0.f;
        #pragma unroll 16
        for (int c = 0; c < 64; ++c) dot = fmaf(ks[c], qs[t][c], dot);
        float vw = dot * 0.125f;
        float4 rj = *reinterpret_cast<const float4*>(&rois[j * 4]);
        float wj = rj.z - rj.x, hj = rj.w - rj.y;
        float f1 = logf(fabsf(0.5f * (rj.x + rj.z) - cxi) / wi + 1e-3f);
        float f2 = logf(fabsf(0.5f * (rj.y + rj.w) - cyi) / hi_ + 1e-3f);
        float f3 = logf(wj / wi);
        float f4 = logf(hj / hi_);
        float gw = 0.f;
        #pragma unroll 8
        for (int m = 0; m < 64; ++m) {
            float hm = g1s[m];
            hm = fmaf(f1, G1s[m], hm);
            hm = fmaf(f2, G1s[64 + m], hm);
            hm = fmaf(f3, G1s[128 + m], hm);
            hm = fmaf(f4, G1s[192 + m], hm);
            hm = fmaxf(hm, 0.f);
            gw = fmaf(hm, G2s[m], gw);
        }
        gw = fmaxf(gw + g2v, 0.f);
        float a = expf(vw) * gw;
        if (j == i) a = 0.f;
        vals[ch] = a;
        rsum += a;
    }
    float s = rsum;
    #pragma unroll
    for (int o = 32; o > 0; o >>= 1) s += __shfl_down(s, o, 64);
    if ((t & 63) == 0) red[t >> 6] = s;
    __syncthreads();
    const float inv = 1.f / (red[0] + red[1] + 1e-10f);
    #pragma unroll
    for (int ch = 0; ch < 8; ++ch)
        att[i * NR + ch * 128 + t] = f2bf(vals[ch] * inv);
}

extern "C" void kernel_launch(void* const* d_in, const int* in_sizes, int n_in,
                              void* d_out, int out_size, void* d_ws, size_t ws_size,
                              hipStream_t stream) {
    const float* feat = (const float*)d_in[0];
    const float* rois = (const float*)d_in[1];
    const float* Wk   = (const float*)d_in[2];
    const float* bk   = (const float*)d_in[3];
    const float* Wq   = (const float*)d_in[4];
    const float* bq   = (const float*)d_in[5];
    const float* Wv   = (const float*)d_in[6];
    const float* bv   = (const float*)d_in[7];
    const float* G1   = (const float*)d_in[8];
    const float* g1   = (const float*)d_in[9];
    const float* G2   = (const float*)d_in[10];
    const float* g2   = (const float*)d_in[11];
    float* out = (float*)d_out;
    char* ws = (char*)d_ws;

    float* kqbuf         = (float*)ws;                                          // 512 KB
    unsigned short* fvb  = (unsigned short*)(ws + (512 << 10));                 // 4 MB
    unsigned short* WvT  = (unsigned short*)(ws + (512 << 10) + (4 << 20));     // 8 MB
    unsigned short* WkqT = (unsigned short*)(ws + (512 << 10) + (12 << 20));    // 512 KB
    unsigned short* vT   = (unsigned short*)(ws + (1024 << 10) + (12 << 20));   // 4 MB
    unsigned short* attb = (unsigned short*)(ws + (1024 << 10) + (16 << 20));   // 2 MB

    prep_kernel<<<2112, 256, 0, stream>>>(feat, Wk, Wq, Wv, fvb, WkqT, WvT);
    gemm_vt_kq<<<136, 256, 0, stream>>>(WvT, fvb, WkqT, bv, bk, bq, vT, kqbuf);
    attn_kernel<<<NR, 128, 0, stream>>>(kqbuf, rois, G1, g1, G2, g2, attb);
    gemm_out<<<dim3(DO / 128, NR / 128), 256, 0, stream>>>(attb, vT, out);
}

// Round 5
// 89.787 us; speedup vs baseline: 4.3076x; 1.2179x over previous
//
#include <hip/hip_runtime.h>
#include <hip/hip_bf16.h>

#define NR 1024
#define DV 2048
#define DMM 64
#define DO 2048

typedef __attribute__((ext_vector_type(8))) __bf16 bf16x8;
typedef __attribute__((ext_vector_type(4))) float f32x4;

__device__ __forceinline__ float relu_f(float x) { return fmaxf(x, 0.f); }

__device__ __forceinline__ unsigned short f2bf(float x) {
    union { float f; unsigned int u; } v; v.f = x;
    unsigned int r = v.u + 0x7fffu + ((v.u >> 16) & 1u);   // RNE
    return (unsigned short)(r >> 16);
}

__device__ __forceinline__ void gload_lds16(const void* g, void* l) {
    __builtin_amdgcn_global_load_lds(
        (const __attribute__((address_space(1))) void*)g,
        (__attribute__((address_space(3))) void*)l, 16, 0, 0);
}

// ---------------- prep: convert_fv + 3 weight transposes + box features ----------------
__device__ __forceinline__ void transpose_tile(
    const float* __restrict__ W, unsigned short* __restrict__ Wt,
    int Ncols, int k0, int o0, float (*ld)[65])
{
    const int t = threadIdx.x;
    const int r = t >> 2;
    const int c0 = (t & 3) * 16;
    #pragma unroll
    for (int i = 0; i < 4; ++i) {
        float4 v = *reinterpret_cast<const float4*>(&W[(size_t)(k0 + r) * Ncols + o0 + c0 + i * 4]);
        ld[c0 + i * 4 + 0][r] = v.x;
        ld[c0 + i * 4 + 1][r] = v.y;
        ld[c0 + i * 4 + 2][r] = v.z;
        ld[c0 + i * 4 + 3][r] = v.w;
    }
    __syncthreads();
    const int o = t >> 2;
    const int kc = (t & 3) * 16;
    unsigned int u[8];
    #pragma unroll
    for (int j = 0; j < 8; ++j) {
        float x0 = ld[o][kc + 2 * j], x1 = ld[o][kc + 2 * j + 1];
        u[j] = (unsigned)f2bf(x0) | ((unsigned)f2bf(x1) << 16);
    }
    uint4* dst = reinterpret_cast<uint4*>(&Wt[(size_t)(o0 + o) * DV + k0 + kc]);
    dst[0] = make_uint4(u[0], u[1], u[2], u[3]);
    dst[1] = make_uint4(u[4], u[5], u[6], u[7]);
}

__global__ __launch_bounds__(256) void prep_kernel(
    const float* __restrict__ feat,
    const float* __restrict__ Wk, const float* __restrict__ Wq, const float* __restrict__ Wv,
    const float* __restrict__ rois,
    unsigned short* __restrict__ fvb, unsigned short* __restrict__ WkqT,
    unsigned short* __restrict__ WvT,
    float4* __restrict__ boxf, float2* __restrict__ boxinv)
{
    __shared__ float ld[64][65];
    const int bid = blockIdx.x;
    if (bid < 1024) {
        const int idx = bid * 256 + threadIdx.x;
        const float4 a = *reinterpret_cast<const float4*>(feat + (size_t)idx * 8);
        const float4 b = *reinterpret_cast<const float4*>(feat + (size_t)idx * 8 + 4);
        uint4 o;
        o.x = (unsigned)f2bf(relu_f(a.x)) | ((unsigned)f2bf(relu_f(a.y)) << 16);
        o.y = (unsigned)f2bf(relu_f(a.z)) | ((unsigned)f2bf(relu_f(a.w)) << 16);
        o.z = (unsigned)f2bf(relu_f(b.x)) | ((unsigned)f2bf(relu_f(b.y)) << 16);
        o.w = (unsigned)f2bf(relu_f(b.z)) | ((unsigned)f2bf(relu_f(b.w)) << 16);
        *reinterpret_cast<uint4*>(fvb + (size_t)idx * 8) = o;
    } else if (bid < 2048) {
        const int idx = bid - 1024;                 // 32x32 tiles of Wv
        transpose_tile(Wv, WvT, DO, (idx >> 5) * 64, (idx & 31) * 64, ld);
    } else if (bid < 2080) {
        transpose_tile(Wk, WkqT, DMM, (bid - 2048) * 64, 0, ld);
    } else if (bid < 2112) {
        transpose_tile(Wq, WkqT + 64 * DV, DMM, (bid - 2080) * 64, 0, ld);
    } else {
        const int idx = (bid - 2112) * 256 + threadIdx.x;   // 0..1023
        const float4 r = *reinterpret_cast<const float4*>(rois + (size_t)idx * 4);
        const float w = r.z - r.x, h = r.w - r.y;
        boxf[idx]   = make_float4(0.5f * (r.x + r.z), 0.5f * (r.y + r.w), __logf(w), __logf(h));
        boxinv[idx] = make_float2(1.f / w, 1.f / h);
    }
}

// ---------------- 128x128 MFMA tile core: acc += A[bm0..][lda] @ Bt[bn0..][ldb]^T ----------------
__device__ __forceinline__ void mfma_tile_128(
    const unsigned short* __restrict__ A, const unsigned short* __restrict__ Bt,
    int K, int lda, int ldb,
    int bm0, int bn0, unsigned short* As, unsigned short* Bs, f32x4 (&acc)[4][4])
{
    const int t = threadIdx.x;
    const int w = t >> 6, lane = t & 63;
    const int wr = w >> 1, wc = w & 1;
    const int srow = lane >> 2, scol = (lane & 3) * 8;
    const int fr = lane & 15, fq = lane >> 4;

    const unsigned short* ga0 = A  + (size_t)(bm0 + w * 16 + srow) * lda + scol;
    const unsigned short* ga1 = A  + (size_t)(bm0 + 64 + w * 16 + srow) * lda + scol;
    const unsigned short* gb0 = Bt + (size_t)(bn0 + w * 16 + srow) * ldb + scol;
    const unsigned short* gb1 = Bt + (size_t)(bn0 + 64 + w * 16 + srow) * ldb + scol;
    unsigned short* la0 = &As[(w * 16) * 32];
    unsigned short* la1 = &As[(64 + w * 16) * 32];
    unsigned short* lb0 = &Bs[(w * 16) * 32];
    unsigned short* lb1 = &Bs[(64 + w * 16) * 32];

    for (int k0 = 0; k0 < K; k0 += 32) {
        gload_lds16(ga0 + k0, la0);
        gload_lds16(ga1 + k0, la1);
        gload_lds16(gb0 + k0, lb0);
        gload_lds16(gb1 + k0, lb1);
        __syncthreads();
        bf16x8 af[4], bfr[4];
        #pragma unroll
        for (int m = 0; m < 4; ++m)
            af[m] = *reinterpret_cast<const bf16x8*>(&As[(wr * 64 + m * 16 + fr) * 32 + fq * 8]);
        #pragma unroll
        for (int n = 0; n < 4; ++n)
            bfr[n] = *reinterpret_cast<const bf16x8*>(&Bs[(wc * 64 + n * 16 + fr) * 32 + fq * 8]);
        #pragma unroll
        for (int m = 0; m < 4; ++m)
            #pragma unroll
            for (int n = 0; n < 4; ++n)
                acc[m][n] = __builtin_amdgcn_mfma_f32_16x16x32_bf16(af[m], bfr[n], acc[m][n], 0, 0, 0);
        __syncthreads();
    }
}

// ---------------- fused vT GEMM (128 blocks) + kq GEMM (8 blocks) ----------------
// vT[DO][NR] = WvT[DO][DV] @ fvb[NR][DV]^T + bv[row]          (bf16 out)
// kqb[NR][128] = fvb[NR][DV] @ WkqT[128][DV]^T + {bk|bq}[col]  (bf16 out)
__global__ __launch_bounds__(256) void gemm_vt_kq(
    const unsigned short* __restrict__ WvT, const unsigned short* __restrict__ fvb,
    const unsigned short* __restrict__ WkqT,
    const float* __restrict__ bv, const float* __restrict__ bk, const float* __restrict__ bq,
    unsigned short* __restrict__ vT, unsigned short* __restrict__ kqb)
{
    __shared__ unsigned short As[128 * 32];
    __shared__ unsigned short Bs[128 * 32];
    const int bid = blockIdx.x;
    const bool is_kq = bid >= 128;
    const unsigned short* A  = is_kq ? fvb  : WvT;
    const unsigned short* Bt = is_kq ? WkqT : fvb;
    const int bm0 = is_kq ? (bid - 128) * 128 : (bid >> 3) * 128;
    const int bn0 = is_kq ? 0 : (bid & 7) * 128;

    f32x4 acc[4][4] = {};
    mfma_tile_128(A, Bt, DV, DV, DV, bm0, bn0, As, Bs, acc);

    const int t = threadIdx.x;
    const int w = t >> 6, lane = t & 63;
    const int wr = w >> 1, wc = w & 1;
    const int fr = lane & 15, fq = lane >> 4;
    if (!is_kq) {
        #pragma unroll
        for (int m = 0; m < 4; ++m)
            #pragma unroll
            for (int r = 0; r < 4; ++r) {
                const int row = bm0 + wr * 64 + m * 16 + fq * 4 + r;
                const float badd = bv[row];
                #pragma unroll
                for (int n = 0; n < 4; ++n) {
                    const int col = bn0 + wc * 64 + n * 16 + fr;
                    vT[(size_t)row * NR + col] = f2bf(acc[m][n][r] + badd);
                }
            }
    } else {
        #pragma unroll
        for (int m = 0; m < 4; ++m)
            #pragma unroll
            for (int r = 0; r < 4; ++r) {
                const int row = bm0 + wr * 64 + m * 16 + fq * 4 + r;
                #pragma unroll
                for (int n = 0; n < 4; ++n) {
                    const int col = wc * 64 + n * 16 + fr;
                    const float badd = (col < 64) ? bk[col] : bq[col - 64];
                    kqb[(size_t)row * 128 + col] = f2bf(acc[m][n][r] + badd);
                }
            }
    }
}

// ---------------- S[i][j] = 0.125 * <k_i, q_j>  (K=64 MFMA GEMM) ----------------
__global__ __launch_bounds__(256) void gemm_s(
    const unsigned short* __restrict__ kqb, float* __restrict__ S)
{
    __shared__ unsigned short As[128 * 32];
    __shared__ unsigned short Bs[128 * 32];
    const int bm0 = blockIdx.y * 128;
    const int bn0 = blockIdx.x * 128;
    f32x4 acc[4][4] = {};
    mfma_tile_128(kqb, kqb + 64, 64, 128, 128, bm0, bn0, As, Bs, acc);
    const int t = threadIdx.x;
    const int w = t >> 6, lane = t & 63;
    const int wr = w >> 1, wc = w & 1;
    const int fr = lane & 15, fq = lane >> 4;
    #pragma unroll
    for (int m = 0; m < 4; ++m)
        #pragma unroll
        for (int r = 0; r < 4; ++r) {
            const int row = bm0 + wr * 64 + m * 16 + fq * 4 + r;
            #pragma unroll
            for (int n = 0; n < 4; ++n) {
                const int col = bn0 + wc * 64 + n * 16 + fr;
                S[(size_t)row * NR + col] = acc[m][n][r] * 0.125f;
            }
        }
}

// ---------------- out GEMM: out[NR][DO] = attb[NR][NR] @ vT[DO][NR]^T ----------------
__global__ __launch_bounds__(256) void gemm_out(
    const unsigned short* __restrict__ attb, const unsigned short* __restrict__ vT,
    float* __restrict__ out)
{
    __shared__ unsigned short As[128 * 32];
    __shared__ unsigned short Bs[128 * 32];
    const int bm0 = blockIdx.y * 128;
    const int bn0 = blockIdx.x * 128;
    f32x4 acc[4][4] = {};
    mfma_tile_128(attb, vT, NR, NR, NR, bm0, bn0, As, Bs, acc);
    const int t = threadIdx.x;
    const int w = t >> 6, lane = t & 63;
    const int wr = w >> 1, wc = w & 1;
    const int fr = lane & 15, fq = lane >> 4;
    #pragma unroll
    for (int m = 0; m < 4; ++m)
        #pragma unroll
        for (int r = 0; r < 4; ++r) {
            const int row = bm0 + wr * 64 + m * 16 + fq * 4 + r;
            #pragma unroll
            for (int n = 0; n < 4; ++n) {
                const int col = bn0 + wc * 64 + n * 16 + fr;
                out[(size_t)row * DO + col] = acc[m][n][r];
            }
        }
}

// ---------------- attention row kernel v2: VALU-only MLP, S precomputed ----------------
// 1024 blocks x 256 threads; thread handles j = ch*256 + t for ch=0..3.
#define MLP_STEP(A_, B_, C_, D_, E_, F_)                                            \
    {                                                                               \
        float h_ = fmaf(ff1[ch], A_, fmaf(ff2[ch], B_, fmaf(ff3[ch], C_,            \
                   fmaf(ff4[ch], D_, E_))));                                        \
        h_ = fmaxf(h_, 0.f);                                                        \
        gw[ch] = fmaf(h_, F_, gw[ch]);                                              \
    }

__global__ __launch_bounds__(256) void attn_kernel(
    const float* __restrict__ S,
    const float4* __restrict__ boxf, const float2* __restrict__ boxinv,
    const float* __restrict__ G1, const float* __restrict__ g1,
    const float* __restrict__ G2, const float* __restrict__ g2,
    unsigned short* __restrict__ att)
{
    __shared__ float G1s[4][64];
    __shared__ float g1s[64];
    __shared__ float G2s[64];
    __shared__ float red[4];
    const int i = blockIdx.x;
    const int t = threadIdx.x;
    if (t < 64) {
        G1s[0][t] = G1[t];
        G1s[1][t] = G1[64 + t];
        G1s[2][t] = G1[128 + t];
        G1s[3][t] = G1[192 + t];
        g1s[t] = g1[t];
        G2s[t] = G2[t];
    }
    __syncthreads();
    const float4 bi = boxf[i];
    const float2 ivi = boxinv[i];
    const float g2v = g2[0];

    float ff1[4], ff2[4], ff3[4], ff4[4], sc[4], gw[4] = {0.f, 0.f, 0.f, 0.f};
    #pragma unroll
    for (int ch = 0; ch < 4; ++ch) {
        const int j = ch * 256 + t;
        const float4 bj = boxf[j];
        sc[ch] = S[(size_t)i * NR + j];
        ff1[ch] = __logf(fmaf(fabsf(bj.x - bi.x), ivi.x, 1e-3f));
        ff2[ch] = __logf(fmaf(fabsf(bj.y - bi.y), ivi.y, 1e-3f));
        ff3[ch] = bj.z - bi.z;
        ff4[ch] = bj.w - bi.w;
    }

    for (int mt = 0; mt < 64; mt += 8) {
        const float4 A0 = *reinterpret_cast<const float4*>(&G1s[0][mt]);
        const float4 A1 = *reinterpret_cast<const float4*>(&G1s[0][mt + 4]);
        const float4 B0 = *reinterpret_cast<const float4*>(&G1s[1][mt]);
        const float4 B1 = *reinterpret_cast<const float4*>(&G1s[1][mt + 4]);
        const float4 C0 = *reinterpret_cast<const float4*>(&G1s[2][mt]);
        const float4 C1 = *reinterpret_cast<const float4*>(&G1s[2][mt + 4]);
        const float4 D0 = *reinterpret_cast<const float4*>(&G1s[3][mt]);
        const float4 D1 = *reinterpret_cast<const float4*>(&G1s[3][mt + 4]);
        const float4 E0 = *reinterpret_cast<const float4*>(&g1s[mt]);
        const float4 E1 = *reinterpret_cast<const float4*>(&g1s[mt + 4]);
        const float4 F0 = *reinterpret_cast<const float4*>(&G2s[mt]);
        const float4 F1 = *reinterpret_cast<const float4*>(&G2s[mt + 4]);
        #pragma unroll
        for (int ch = 0; ch < 4; ++ch) {
            MLP_STEP(A0.x, B0.x, C0.x, D0.x, E0.x, F0.x)
            MLP_STEP(A0.y, B0.y, C0.y, D0.y, E0.y, F0.y)
            MLP_STEP(A0.z, B0.z, C0.z, D0.z, E0.z, F0.z)
            MLP_STEP(A0.w, B0.w, C0.w, D0.w, E0.w, F0.w)
            MLP_STEP(A1.x, B1.x, C1.x, D1.x, E1.x, F1.x)
            MLP_STEP(A1.y, B1.y, C1.y, D1.y, E1.y, F1.y)
            MLP_STEP(A1.z, B1.z, C1.z, D1.z, E1.z, F1.z)
            MLP_STEP(A1.w, B1.w, C1.w, D1.w, E1.w, F1.w)
        }
    }

    float vals[4];
    float rsum = 0.f;
    #pragma unroll
    for (int ch = 0; ch < 4; ++ch) {
        const float gwp = fmaxf(gw[ch] + g2v, 0.f);
        float a = __expf(sc[ch]) * gwp;
        if (ch * 256 + t == i) a = 0.f;
        vals[ch] = a;
        rsum += a;
    }
    #pragma unroll
    for (int o = 32; o > 0; o >>= 1) rsum += __shfl_down(rsum, o, 64);
    if ((t & 63) == 0) red[t >> 6] = rsum;
    __syncthreads();
    const float inv = 1.f / (red[0] + red[1] + red[2] + red[3] + 1e-10f);
    #pragma unroll
    for (int ch = 0; ch < 4; ++ch)
        att[(size_t)i * NR + ch * 256 + t] = f2bf(vals[ch] * inv);
}

extern "C" void kernel_launch(void* const* d_in, const int* in_sizes, int n_in,
                              void* d_out, int out_size, void* d_ws, size_t ws_size,
                              hipStream_t stream) {
    const float* feat = (const float*)d_in[0];
    const float* rois = (const float*)d_in[1];
    const float* Wk   = (const float*)d_in[2];
    const float* bk   = (const float*)d_in[3];
    const float* Wq   = (const float*)d_in[4];
    const float* bq   = (const float*)d_in[5];
    const float* Wv   = (const float*)d_in[6];
    const float* bv   = (const float*)d_in[7];
    const float* G1   = (const float*)d_in[8];
    const float* g1   = (const float*)d_in[9];
    const float* G2   = (const float*)d_in[10];
    const float* g2   = (const float*)d_in[11];
    float* out = (float*)d_out;
    char* ws = (char*)d_ws;

    unsigned short* kqb  = (unsigned short*)ws;                                  // 256 KB
    float4* boxf         = (float4*)(ws + (256 << 10));                          // 16 KB
    float2* boxinv       = (float2*)(ws + (272 << 10));                          // 8 KB
    unsigned short* fvb  = (unsigned short*)(ws + (512 << 10));                  // 4 MB
    unsigned short* WvT  = (unsigned short*)(ws + (512 << 10) + (4 << 20));      // 8 MB
    unsigned short* WkqT = (unsigned short*)(ws + (512 << 10) + (12 << 20));     // 512 KB
    unsigned short* vT   = (unsigned short*)(ws + (1024 << 10) + (12 << 20));    // 4 MB
    unsigned short* attb = (unsigned short*)(ws + (1024 << 10) + (16 << 20));    // 2 MB
    float* Sbuf          = (float*)(ws + (1024 << 10) + (18 << 20));             // 4 MB

    prep_kernel<<<2116, 256, 0, stream>>>(feat, Wk, Wq, Wv, rois, fvb, WkqT, WvT, boxf, boxinv);
    gemm_vt_kq<<<136, 256, 0, stream>>>(WvT, fvb, WkqT, bv, bk, bq, vT, kqb);
    gemm_s<<<dim3(8, 8), 256, 0, stream>>>(kqb, Sbuf);
    attn_kernel<<<NR, 256, 0, stream>>>(Sbuf, boxf, boxinv, G1, g1, G2, g2, attb);
    gemm_out<<<dim3(DO / 128, NR / 128), 256, 0, stream>>>(attb, vT, out);
}